// Round 1
// baseline (529.336 us; speedup 1.0000x reference)
//
#include <hip/hip_runtime.h>
#include <stdint.h>

typedef unsigned short u16;
typedef __attribute__((ext_vector_type(8))) short bf16x8;
typedef __attribute__((ext_vector_type(4))) float f32x4;

#define DEVI static __device__ __forceinline__

DEVI u16 f2bf(float f){
  union { float f; uint32_t u; } c; c.f = f;
  uint32_t u = c.u;
  u += 0x7FFFu + ((u >> 16) & 1u);   // RNE
  return (u16)(u >> 16);
}
DEVI float b2f(u16 h){
  union { uint32_t u; float f; } c; c.u = ((uint32_t)h) << 16;
  return c.f;
}
DEVI float loadf(float v){ return v; }
DEVI float loadf(u16 v){ return b2f(v); }

// ---------------------------------------------------------------------------
// GEMM: C[m,n] = sum_k A[m,k] * Bt[n,k]  (+ optional bias, bf16 or f32 out)
// 256 threads = 4 waves in 2x2; per-wave tile (FM*16) x (FN*16).
// BIAS_MODE: 0 none, 1 bias[row] (M), 2 bias[col] (N).
// ---------------------------------------------------------------------------
template<int BM,int BN,int FM,int FN,int BIAS_MODE,bool OUT_BF16,bool ACCUM>
__global__ __launch_bounds__(256) void gemm_bt(
    const u16* __restrict__ A, long long strideA, int lda,
    const u16* __restrict__ B, long long strideB, int ldb,
    void* __restrict__ C, long long strideC, int ldc,
    const float* __restrict__ bias, int K)
{
  constexpr int BK  = 32;
  constexpr int BKP = BK + 8;          // +16B pad: breaks 64B-stride bank aliasing
  constexpr int WTM = FM*16, WTN = FN*16;
  static_assert(BM == 2*WTM && BN == 2*WTN, "2x2 wave layout");
  __shared__ u16 As[BM*BKP];
  __shared__ u16 Bs[BN*BKP];

  const int z = blockIdx.z;
  A += (long long)z * strideA;
  B += (long long)z * strideB;

  const int tid  = threadIdx.x;
  const int lane = tid & 63, wid = tid >> 6;
  const int wr = wid >> 1, wc = wid & 1;
  const long long bm0 = (long long)blockIdx.y * BM;
  const long long bn0 = (long long)blockIdx.x * BN;

  constexpr int COLS = BK/8;                // 4 x 16B chunks per row
  constexpr int ROWS_PER_TRIP = 256/COLS;   // 64
  constexpr int TRIPS_A = BM/ROWS_PER_TRIP;
  constexpr int TRIPS_B = BN/ROWS_PER_TRIP;
  const int sr = tid / COLS;
  const int sc = (tid % COLS) * 8;

  f32x4 acc[FM][FN] = {};

  for(int k0 = 0; k0 < K; k0 += BK){
    __syncthreads();
    #pragma unroll
    for(int t=0;t<TRIPS_A;t++){
      int r = sr + t*ROWS_PER_TRIP;
      bf16x8 v = *reinterpret_cast<const bf16x8*>(&A[(bm0 + r)*lda + k0 + sc]);
      *reinterpret_cast<bf16x8*>(&As[r*BKP + sc]) = v;
    }
    #pragma unroll
    for(int t=0;t<TRIPS_B;t++){
      int r = sr + t*ROWS_PER_TRIP;
      bf16x8 v = *reinterpret_cast<const bf16x8*>(&B[(bn0 + r)*ldb + k0 + sc]);
      *reinterpret_cast<bf16x8*>(&Bs[r*BKP + sc]) = v;
    }
    __syncthreads();
    const int fr = lane & 15, fk = (lane >> 4) * 8;
    bf16x8 af[FM], bfg[FN];
    #pragma unroll
    for(int m=0;m<FM;m++)
      af[m] = *reinterpret_cast<const bf16x8*>(&As[(wr*WTM + m*16 + fr)*BKP + fk]);
    #pragma unroll
    for(int n=0;n<FN;n++)
      bfg[n] = *reinterpret_cast<const bf16x8*>(&Bs[(wc*WTN + n*16 + fr)*BKP + fk]);
    #pragma unroll
    for(int m=0;m<FM;m++)
      #pragma unroll
      for(int n=0;n<FN;n++)
        acc[m][n] = __builtin_amdgcn_mfma_f32_16x16x32_bf16(af[m], bfg[n], acc[m][n], 0, 0, 0);
  }

  // C/D layout (verified m89): col = lane&15, row = (lane>>4)*4 + reg
  const int lr = (lane >> 4) * 4, lc = lane & 15;
  #pragma unroll
  for(int m=0;m<FM;m++){
    #pragma unroll
    for(int n=0;n<FN;n++){
      #pragma unroll
      for(int r=0;r<4;r++){
        long long row = bm0 + wr*WTM + m*16 + lr + r;
        long long col = bn0 + wc*WTN + n*16 + lc;
        float v = acc[m][n][r];
        if(BIAS_MODE == 1) v += bias[(int)row];
        if(BIAS_MODE == 2) v += bias[(int)col];
        long long idx = row * (long long)ldc + col;
        if(OUT_BF16){
          u16* Cp = (u16*)C + (long long)z * strideC;
          Cp[idx] = f2bf(v);
        } else {
          float* Cp = (float*)C + (long long)z * strideC;
          if(ACCUM) Cp[idx] += v; else Cp[idx] = v;
        }
      }
    }
  }
}

// ---------------------------------------------------------------------------
// Row softmax: one block per row, width W (compile-time), bf16 output.
// In-place safe (reads complete before writes in the same block).
// ---------------------------------------------------------------------------
template<typename TIN, int W>
__global__ __launch_bounds__(256) void softmax_rows(const TIN* __restrict__ in,
                                                    u16* __restrict__ out)
{
  constexpr int NC = W/256;
  const long long row = blockIdx.x;
  const TIN* ip = in + row * W;
  u16* op = out + row * W;
  const int t = threadIdx.x;
  const int lane = t & 63, wid = t >> 6;
  float rv[NC];
  float m = -3.0e38f;
  #pragma unroll
  for(int j=0;j<NC;j++){
    float v = loadf(ip[j*256 + t]);
    rv[j] = v;
    m = fmaxf(m, v);
  }
  #pragma unroll
  for(int o=32;o;o>>=1) m = fmaxf(m, __shfl_xor(m, o));
  __shared__ float sred[4];
  if(lane == 0) sred[wid] = m;
  __syncthreads();
  m = fmaxf(fmaxf(sred[0], sred[1]), fmaxf(sred[2], sred[3]));
  float s = 0.f;
  #pragma unroll
  for(int j=0;j<NC;j++){ float e = __expf(rv[j] - m); rv[j] = e; s += e; }
  #pragma unroll
  for(int o=32;o;o>>=1) s += __shfl_xor(s, o);
  __syncthreads();
  if(lane == 0) sred[wid] = s;
  __syncthreads();
  s = sred[0] + sred[1] + sred[2] + sred[3];
  float inv = 1.0f / s;
  #pragma unroll
  for(int j=0;j<NC;j++) op[j*256 + t] = f2bf(rv[j] * inv);
}

// f32 -> bf16 cast (float4 per thread)
__global__ __launch_bounds__(256) void castk(const float* __restrict__ in,
                                             u16* __restrict__ out, int n4)
{
  int i = blockIdx.x*256 + threadIdx.x;
  if(i >= n4) return;
  float4 v = reinterpret_cast<const float4*>(in)[i];
  ushort4 o;
  o.x = f2bf(v.x); o.y = f2bf(v.y); o.z = f2bf(v.z); o.w = f2bf(v.w);
  reinterpret_cast<ushort4*>(out)[i] = o;
}

// x f32 [b][512][4096] -> xfb bf16 [b][512][4096] and xfT bf16 [b][4096][512]
__global__ __launch_bounds__(256) void transpose_cast(
    const float* __restrict__ x, u16* __restrict__ xfb, u16* __restrict__ xfT)
{
  __shared__ float tile[32][33];
  const int b  = blockIdx.z;
  const int n0 = blockIdx.x * 32, c0 = blockIdx.y * 32;
  const int tx = threadIdx.x, ty = threadIdx.y;  // 32 x 8
  const float* xp = x + (long long)b * 512 * 4096;
  #pragma unroll
  for(int i=0;i<4;i++){
    int c = c0 + ty + i*8;
    float v = xp[(long long)c*4096 + n0 + tx];
    tile[ty + i*8][tx] = v;
    xfb[((long long)b*512 + c)*4096 + n0 + tx] = f2bf(v);
  }
  __syncthreads();
  #pragma unroll
  for(int i=0;i<4;i++){
    int n = n0 + ty + i*8;
    xfT[((long long)b*4096 + n)*512 + c0 + tx] = f2bf(tile[tx][ty + i*8]);
  }
}

// posT = gamma*posT + xfT ; chanT = beta*chanT + xfT   (all [b][n][c] bf16)
__global__ __launch_bounds__(256) void combine_pc(
    u16* __restrict__ posT, u16* __restrict__ chanT, const u16* __restrict__ xfT,
    const float* __restrict__ gamma, const float* __restrict__ beta, long long n)
{
  long long i = (long long)blockIdx.x*256 + threadIdx.x;
  if(i >= n) return;
  float g = gamma[0], be = beta[0];
  float xv = b2f(xfT[i]);
  posT[i]  = f2bf(g  * b2f(posT[i])  + xv);
  chanT[i] = f2bf(be * b2f(chanT[i]) + xv);
}

// per-channel mean / inv-std over (b, n): one block per channel
__global__ __launch_bounds__(256) void bn_stats(const float* __restrict__ y,
                                                float* __restrict__ stat)
{
  const int o = blockIdx.x, t = threadIdx.x;
  const int lane = t & 63, wid = t >> 6;
  float s = 0.f, ss = 0.f;
  for(int b=0;b<4;b++){
    const float* p = y + ((long long)b*512 + o)*4096;
    for(int i=t;i<4096;i+=256){ float v = p[i]; s += v; ss += v*v; }
  }
  #pragma unroll
  for(int off=32;off;off>>=1){ s += __shfl_xor(s, off); ss += __shfl_xor(ss, off); }
  __shared__ float sred[8];
  if(lane == 0){ sred[wid] = s; sred[wid+4] = ss; }
  __syncthreads();
  if(t == 0){
    float S  = sred[0]+sred[1]+sred[2]+sred[3];
    float SS = sred[4]+sred[5]+sred[6]+sred[7];
    float mean = S * (1.f/16384.f);
    float var  = SS * (1.f/16384.f) - mean*mean;
    stat[o*2]   = mean;
    stat[o*2+1] = rsqrtf(var + 1e-5f);
  }
}

// in-place: y = relu((y-mean)*rstd*w + b), float4 per thread
__global__ __launch_bounds__(256) void bn_apply(float* __restrict__ y,
    const float* __restrict__ stat, const float* __restrict__ w,
    const float* __restrict__ bb)
{
  long long i = (long long)blockIdx.x*256 + threadIdx.x;   // float4 index
  float4 v = reinterpret_cast<float4*>(y)[i];
  int o = (int)(((i*4) >> 12) & 511);
  float mean = stat[o*2], rstd = stat[o*2+1];
  float sc = w[o] * rstd;
  float sh = bb[o] - mean * sc;
  v.x = fmaxf(v.x*sc + sh, 0.f);
  v.y = fmaxf(v.y*sc + sh, 0.f);
  v.z = fmaxf(v.z*sc + sh, 0.f);
  v.w = fmaxf(v.w*sc + sh, 0.f);
  reinterpret_cast<float4*>(y)[i] = v;
}

extern "C" void kernel_launch(void* const* d_in, const int* in_sizes, int n_in,
                              void* d_out, int out_size, void* d_ws, size_t ws_size,
                              hipStream_t stream)
{
  const float* x     = (const float*)d_in[0];
  const float* qw    = (const float*)d_in[1];
  const float* qb    = (const float*)d_in[2];
  const float* kw    = (const float*)d_in[3];
  const float* kb    = (const float*)d_in[4];
  const float* vw    = (const float*)d_in[5];
  const float* vb    = (const float*)d_in[6];
  const float* gamma = (const float*)d_in[7];
  const float* beta  = (const float*)d_in[8];
  const float* fw    = (const float*)d_in[9];
  const float* fb    = (const float*)d_in[10];
  const float* bnw   = (const float*)d_in[11];
  const float* bnb   = (const float*)d_in[12];
  float* out = (float*)d_out;
  (void)in_sizes; (void)n_in; (void)out_size;

  char* base = (char*)d_ws;
  size_t off = 0;
  auto alloc = [&](size_t bytes)->char* {
    char* p = base + off;
    off += (bytes + 255) & ~(size_t)255;
    return p;
  };
  const long long NB = 4, Cc = 512, Nn = 4096, CQ = 64;

  u16* xfT   = (u16*)alloc((size_t)NB*Nn*Cc*2);   // [b][n][c]
  u16* xfb   = (u16*)alloc((size_t)NB*Cc*Nn*2);   // [b][c][n]
  u16* posT  = xfb;   // ALIAS: xfb is dead after the energy GEMM; posT written later
  u16* qwb   = (u16*)alloc((size_t)CQ*Cc*2);
  u16* kwb   = (u16*)alloc((size_t)CQ*Cc*2);
  u16* vwb   = (u16*)alloc((size_t)Cc*Cc*2);
  u16* fwb   = (u16*)alloc((size_t)Cc*2*Cc*2);    // [512][1024]
  u16* qT    = (u16*)alloc((size_t)NB*Nn*CQ*2);   // [b][n][cq]
  u16* kT    = (u16*)alloc((size_t)NB*Nn*CQ*2);
  u16* vB    = (u16*)alloc((size_t)NB*Cc*Nn*2);   // [b][c][n]
  u16* chanT = (u16*)alloc((size_t)NB*Nn*Cc*2);   // [b][n][c]
  float* stat= (float*)alloc((size_t)Cc*2*4);
  const size_t ATT = (size_t)Nn*Nn*2;             // one batch of scores/att (bf16)
  int natt = (ws_size >= off + 2*ATT) ? 2 : 1;    // 2-batch pipeline if ws allows
  u16* att   = (u16*)alloc((size_t)natt*ATT);
  float* energy = (float*)att;                    // ALIAS: dead before att written
  u16* catt  = (u16*)((char*)att + (size_t)NB*Cc*Cc*4);

  // --- weights to bf16 ---
  castk<<<dim3(32),  dim3(256), 0, stream>>>(qw, qwb, 8192);
  castk<<<dim3(32),  dim3(256), 0, stream>>>(kw, kwb, 8192);
  castk<<<dim3(256), dim3(256), 0, stream>>>(vw, vwb, 65536);
  castk<<<dim3(512), dim3(256), 0, stream>>>(fw, fwb, 131072);
  // --- x -> xfb, xfT ---
  transpose_cast<<<dim3(128,16,4), dim3(32,8), 0, stream>>>(x, xfb, xfT);

  // --- projections: qT[i,o]=xfT.qw^T+qb ; kT ; v[o,n]=vw.xfT^T+vb ---
  gemm_bt<128,64,4,2,2,true,false><<<dim3(1,32,4), dim3(256), 0, stream>>>(
      xfT, Nn*Cc, 512, qwb, 0, 512, qT, Nn*CQ, 64, qb, 512);
  gemm_bt<128,64,4,2,2,true,false><<<dim3(1,32,4), dim3(256), 0, stream>>>(
      xfT, Nn*Cc, 512, kwb, 0, 512, kT, Nn*CQ, 64, kb, 512);
  gemm_bt<128,128,4,4,1,true,false><<<dim3(32,4,4), dim3(256), 0, stream>>>(
      vwb, 0, 512, xfT, Nn*Cc, 512, vB, Cc*Nn, 4096, vb, 512);

  // --- channel attention: energy = xf.xf^T ; catt = softmax ; chanT = xfT.catt^T ---
  gemm_bt<64,64,2,2,0,false,false><<<dim3(8,8,4), dim3(256), 0, stream>>>(
      xfb, Cc*Nn, 4096, xfb, Cc*Nn, 4096, energy, Cc*Cc, 512, nullptr, 4096);
  softmax_rows<float,512><<<dim3(2048), dim3(256), 0, stream>>>(energy, catt);
  gemm_bt<128,128,4,4,0,true,false><<<dim3(4,32,4), dim3(256), 0, stream>>>(
      xfT, Nn*Cc, 512, catt, Cc*Cc, 512, chanT, Nn*Cc, 512, nullptr, 512);

  // --- position attention (paired batches for full-GPU posT GEMM) ---
  for(int pb = 0; pb < 4; pb += natt){
    int nb = (4 - pb < natt) ? (4 - pb) : natt;
    for(int i = 0; i < nb; i++){
      int b = pb + i;
      gemm_bt<128,128,4,4,0,true,false><<<dim3(32,32,1), dim3(256), 0, stream>>>(
          qT + (long long)b*Nn*CQ, 0, 64, kT + (long long)b*Nn*CQ, 0, 64,
          att + (size_t)i*Nn*Nn, 0, 4096, nullptr, 64);
      softmax_rows<u16,4096><<<dim3(4096), dim3(256), 0, stream>>>(
          att + (size_t)i*Nn*Nn, att + (size_t)i*Nn*Nn);
    }
    // posT[i,c] = sum_j att[i,j] * v[c,j]
    gemm_bt<128,128,4,4,0,true,false><<<dim3(4,32,nb), dim3(256), 0, stream>>>(
        att, (long long)Nn*Nn, 4096, vB + (long long)pb*Cc*Nn, Cc*Nn, 4096,
        posT + (long long)pb*Nn*Cc, Nn*Cc, 512, nullptr, 4096);
  }

  // --- residual/scale: posT = g*posT + xfT ; chanT = b*chanT + xfT ---
  combine_pc<<<dim3(32768), dim3(256), 0, stream>>>(posT, chanT, xfT, gamma, beta,
                                                    NB*Nn*Cc);

  // --- fusion conv: y = fw1.pos_out + fw2.chan_out + fb  (into d_out, f32) ---
  gemm_bt<128,128,4,4,0,false,false><<<dim3(32,4,4), dim3(256), 0, stream>>>(
      fwb, 0, 1024, posT, Nn*Cc, 512, out, Cc*Nn, 4096, nullptr, 512);
  gemm_bt<128,128,4,4,1,false,true><<<dim3(32,4,4), dim3(256), 0, stream>>>(
      fwb + 512, 0, 1024, chanT, Nn*Cc, 512, out, Cc*Nn, 4096, fb, 512);

  // --- BN (batch stats) + ReLU ---
  bn_stats<<<dim3(512), dim3(256), 0, stream>>>(out, stat);
  bn_apply<<<dim3(8192), dim3(256), 0, stream>>>(out, stat, bnw, bnb);
}

// Round 2
// 405.383 us; speedup vs baseline: 1.3058x; 1.3058x over previous
//
#include <hip/hip_runtime.h>
#include <stdint.h>

typedef unsigned short u16;
typedef __attribute__((ext_vector_type(8))) short bf16x8;
typedef __attribute__((ext_vector_type(4))) float f32x4;

#define DEVI static __device__ __forceinline__

DEVI u16 f2bf(float f){
  union { float f; uint32_t u; } c; c.f = f;
  uint32_t u = c.u;
  u += 0x7FFFu + ((u >> 16) & 1u);   // RNE
  return (u16)(u >> 16);
}
DEVI float b2f(u16 h){
  union { uint32_t u; float f; } c; c.u = ((uint32_t)h) << 16;
  return c.f;
}

// async global->LDS, 16B per lane. LDS dest = wave-uniform base + lane*16.
DEVI void gload16(const u16* g, u16* l){
  __builtin_amdgcn_global_load_lds(
      (const __attribute__((address_space(1))) unsigned int*)g,
      (__attribute__((address_space(3))) unsigned int*)l, 16, 0, 0);
}

// ---------------------------------------------------------------------------
// GEMM: C[m,n] = sum_k A[m,k] * Bt[n,k]
// m97 structure: global_load_lds width=16 staging, linear LDS, 2-barrier loop.
// LDS XOR-swizzle (both-sides): source slot pre-swizzled, fragment read
// swizzled -> 2-way banks (free).
// BIAS: 0 none, 1 bias[row], 2 bias[col]
// EPI : 0 f32 store, 1 f32 +=, 2 bf16 store, 3 bf16 cscale[0]*v + xadd[row,col]
// ---------------------------------------------------------------------------
template<int BM,int BN,int FM,int FN,int BIAS,int EPI>
__global__ __launch_bounds__(256) void gemm_bt(
    const u16* __restrict__ A, long long strideA, int lda,
    const u16* __restrict__ B, long long strideB, int ldb,
    void* __restrict__ C, long long strideC, int ldc,
    const float* __restrict__ bias, int K,
    const float* __restrict__ cscale, const u16* __restrict__ xadd,
    long long strideX, int ldx)
{
  constexpr int BK  = 32;                 // 64B per LDS row
  constexpr int WTM = FM*16, WTN = FN*16;
  static_assert(BM == 2*WTM && BN == 2*WTN, "2x2 wave layout");
  __shared__ u16 As[BM*BK];
  __shared__ u16 Bs[BN*BK];

  const int z = blockIdx.z;
  const u16* Ab = A + (long long)z * strideA;
  const u16* Bb = B + (long long)z * strideB;

  const int tid  = threadIdx.x;
  const int lane = tid & 63, wid = tid >> 6;
  const int wr = wid >> 1, wc = wid & 1;
  const long long bm0 = (long long)blockIdx.y * BM;
  const long long bn0 = (long long)blockIdx.x * BN;

  // staging: wave w covers 16 rows per trip (1KB), lane -> row (lane>>2),
  // source slot pre-swizzled so LDS holds the swizzled layout linearly.
  const int srow  = lane >> 2;
  const int scol  = (((lane & 3) ^ ((lane >> 3) & 3))) * 8;   // bf16 col
  const int wrow  = wid * 16 + srow;
  constexpr int TA = BM/64, TB = BN/64;

  // fragment read: row fr, k-slot (lane>>4), swizzled by (row>>1)&3
  const int fr  = lane & 15;
  const int sl8 = ((lane >> 4) ^ ((lane >> 1) & 3)) * 8;

  f32x4 acc[FM][FN] = {};

  for(int k0 = 0; k0 < K; k0 += BK){
    __syncthreads();                       // protect LDS reuse
    #pragma unroll
    for(int t=0;t<TA;t++)
      gload16(&Ab[(bm0 + t*64 + wrow)*lda + k0 + scol],
              &As[(t*64 + wid*16)*BK]);
    #pragma unroll
    for(int t=0;t<TB;t++)
      gload16(&Bb[(bn0 + t*64 + wrow)*ldb + k0 + scol],
              &Bs[(t*64 + wid*16)*BK]);
    __syncthreads();                       // drains vmcnt before ds_read

    bf16x8 af[FM], bg[FN];
    #pragma unroll
    for(int m=0;m<FM;m++)
      af[m] = *reinterpret_cast<const bf16x8*>(&As[(wr*WTM + m*16 + fr)*BK + sl8]);
    #pragma unroll
    for(int n=0;n<FN;n++)
      bg[n] = *reinterpret_cast<const bf16x8*>(&Bs[(wc*WTN + n*16 + fr)*BK + sl8]);
    #pragma unroll
    for(int m=0;m<FM;m++)
      #pragma unroll
      for(int n=0;n<FN;n++)
        acc[m][n] = __builtin_amdgcn_mfma_f32_16x16x32_bf16(af[m], bg[n], acc[m][n], 0, 0, 0);
  }

  // C/D layout (verified m89): col = lane&15, row = (lane>>4)*4 + reg
  const int lr = (lane >> 4) * 4, lc = lane & 15;
  float g = (EPI == 3) ? cscale[0] : 0.f;
  #pragma unroll
  for(int m=0;m<FM;m++){
    #pragma unroll
    for(int n=0;n<FN;n++){
      #pragma unroll
      for(int r=0;r<4;r++){
        long long row = bm0 + wr*WTM + m*16 + lr + r;
        long long col = bn0 + wc*WTN + n*16 + lc;
        float v = acc[m][n][r];
        if(BIAS == 1) v += bias[(int)row];
        if(BIAS == 2) v += bias[(int)col];
        long long idx = row * (long long)ldc + col;
        if(EPI == 0){
          ((float*)C + (long long)z*strideC)[idx] = v;
        } else if(EPI == 1){
          ((float*)C + (long long)z*strideC)[idx] += v;
        } else if(EPI == 2){
          ((u16*)C + (long long)z*strideC)[idx] = f2bf(v);
        } else {
          float xv = b2f(xadd[(long long)z*strideX + row*(long long)ldx + col]);
          ((u16*)C + (long long)z*strideC)[idx] = f2bf(g * v + xv);
        }
      }
    }
  }
}

// ---------------------------------------------------------------------------
// Row softmax, f32 in -> bf16 out (for channel energy, W=512)
// ---------------------------------------------------------------------------
template<int W>
__global__ __launch_bounds__(256) void softmax_rows_f32(const float* __restrict__ in,
                                                        u16* __restrict__ out)
{
  constexpr int NC = W/256;
  const long long row = blockIdx.x;
  const float* ip = in + row * W;
  u16* op = out + row * W;
  const int t = threadIdx.x;
  const int lane = t & 63, wid = t >> 6;
  float rv[NC];
  float m = -3.0e38f;
  #pragma unroll
  for(int j=0;j<NC;j++){ float v = ip[j*256 + t]; rv[j] = v; m = fmaxf(m, v); }
  #pragma unroll
  for(int o=32;o;o>>=1) m = fmaxf(m, __shfl_xor(m, o));
  __shared__ float sred[4];
  if(lane == 0) sred[wid] = m;
  __syncthreads();
  m = fmaxf(fmaxf(sred[0], sred[1]), fmaxf(sred[2], sred[3]));
  float s = 0.f;
  #pragma unroll
  for(int j=0;j<NC;j++){ float e = __expf(rv[j] - m); rv[j] = e; s += e; }
  #pragma unroll
  for(int o=32;o;o>>=1) s += __shfl_xor(s, o);
  __syncthreads();
  if(lane == 0) sred[wid] = s;
  __syncthreads();
  s = sred[0] + sred[1] + sred[2] + sred[3];
  float inv = 1.0f / s;
  #pragma unroll
  for(int j=0;j<NC;j++) op[j*256 + t] = f2bf(rv[j] * inv);
}

// ---------------------------------------------------------------------------
// Row softmax bf16 in-place, vectorized bf16x8 (W=4096)
// ---------------------------------------------------------------------------
template<int W>
__global__ __launch_bounds__(256) void softmax_rows_bf16(u16* __restrict__ att)
{
  constexpr int NC = W/2048;                 // bf16x8 chunks per thread
  const long long row = blockIdx.x;
  u16* p = att + row * W;
  const int t = threadIdx.x;
  const int lane = t & 63, wid = t >> 6;
  float rv[NC*8];
  float m = -3.0e38f;
  #pragma unroll
  for(int c=0;c<NC;c++){
    bf16x8 v = *reinterpret_cast<const bf16x8*>(&p[c*2048 + t*8]);
    #pragma unroll
    for(int j=0;j<8;j++){ float f = b2f((u16)v[j]); rv[c*8+j] = f; m = fmaxf(m, f); }
  }
  #pragma unroll
  for(int o=32;o;o>>=1) m = fmaxf(m, __shfl_xor(m, o));
  __shared__ float sred[4];
  if(lane == 0) sred[wid] = m;
  __syncthreads();
  m = fmaxf(fmaxf(sred[0], sred[1]), fmaxf(sred[2], sred[3]));
  float s = 0.f;
  #pragma unroll
  for(int j=0;j<NC*8;j++){ float e = __expf(rv[j] - m); rv[j] = e; s += e; }
  #pragma unroll
  for(int o=32;o;o>>=1) s += __shfl_xor(s, o);
  __syncthreads();
  if(lane == 0) sred[wid] = s;
  __syncthreads();
  s = sred[0] + sred[1] + sred[2] + sred[3];
  float inv = 1.0f / s;
  #pragma unroll
  for(int c=0;c<NC;c++){
    bf16x8 o;
    #pragma unroll
    for(int j=0;j<8;j++) o[j] = (short)f2bf(rv[c*8+j] * inv);
    *reinterpret_cast<bf16x8*>(&p[c*2048 + t*8]) = o;
  }
}

// f32 -> bf16 cast (float4 per thread)
__global__ __launch_bounds__(256) void castk(const float* __restrict__ in,
                                             u16* __restrict__ out, int n4)
{
  int i = blockIdx.x*256 + threadIdx.x;
  if(i >= n4) return;
  float4 v = reinterpret_cast<const float4*>(in)[i];
  ushort4 o;
  o.x = f2bf(v.x); o.y = f2bf(v.y); o.z = f2bf(v.z); o.w = f2bf(v.w);
  reinterpret_cast<ushort4*>(out)[i] = o;
}

__global__ void concat_bias(const float* __restrict__ a, const float* __restrict__ b,
                            float* __restrict__ o)
{
  int t = threadIdx.x;
  o[t] = (t < 64) ? a[t] : b[t-64];
}

// x f32 [b][512][4096] -> xfb bf16 [b][512][4096] and xfT bf16 [b][4096][512]
__global__ __launch_bounds__(256) void transpose_cast(
    const float* __restrict__ x, u16* __restrict__ xfb, u16* __restrict__ xfT)
{
  __shared__ float tile[32][33];
  const int b  = blockIdx.z;
  const int n0 = blockIdx.x * 32, c0 = blockIdx.y * 32;
  const int tx = threadIdx.x, ty = threadIdx.y;  // 32 x 8
  const float* xp = x + (long long)b * 512 * 4096;
  #pragma unroll
  for(int i=0;i<4;i++){
    int c = c0 + ty + i*8;
    float v = xp[(long long)c*4096 + n0 + tx];
    tile[ty + i*8][tx] = v;
    xfb[((long long)b*512 + c)*4096 + n0 + tx] = f2bf(v);
  }
  __syncthreads();
  #pragma unroll
  for(int i=0;i<4;i++){
    int n = n0 + ty + i*8;
    xfT[((long long)b*4096 + n)*512 + c0 + tx] = f2bf(tile[tx][ty + i*8]);
  }
}

// per-channel mean / inv-std over (b, n): one block per channel
__global__ __launch_bounds__(256) void bn_stats(const float* __restrict__ y,
                                                float* __restrict__ stat)
{
  const int o = blockIdx.x, t = threadIdx.x;
  const int lane = t & 63, wid = t >> 6;
  float s = 0.f, ss = 0.f;
  for(int b=0;b<4;b++){
    const float* p = y + ((long long)b*512 + o)*4096;
    for(int i=t;i<4096;i+=256){ float v = p[i]; s += v; ss += v*v; }
  }
  #pragma unroll
  for(int off=32;off;off>>=1){ s += __shfl_xor(s, off); ss += __shfl_xor(ss, off); }
  __shared__ float sred[8];
  if(lane == 0){ sred[wid] = s; sred[wid+4] = ss; }
  __syncthreads();
  if(t == 0){
    float S  = sred[0]+sred[1]+sred[2]+sred[3];
    float SS = sred[4]+sred[5]+sred[6]+sred[7];
    float mean = S * (1.f/16384.f);
    float var  = SS * (1.f/16384.f) - mean*mean;
    stat[o*2]   = mean;
    stat[o*2+1] = rsqrtf(var + 1e-5f);
  }
}

// in-place: y = relu((y-mean)*rstd*w + b), float4 per thread
__global__ __launch_bounds__(256) void bn_apply(float* __restrict__ y,
    const float* __restrict__ stat, const float* __restrict__ w,
    const float* __restrict__ bb)
{
  long long i = (long long)blockIdx.x*256 + threadIdx.x;   // float4 index
  float4 v = reinterpret_cast<float4*>(y)[i];
  int o = (int)(((i*4) >> 12) & 511);
  float mean = stat[o*2], rstd = stat[o*2+1];
  float sc = w[o] * rstd;
  float sh = bb[o] - mean * sc;
  v.x = fmaxf(v.x*sc + sh, 0.f);
  v.y = fmaxf(v.y*sc + sh, 0.f);
  v.z = fmaxf(v.z*sc + sh, 0.f);
  v.w = fmaxf(v.w*sc + sh, 0.f);
  reinterpret_cast<float4*>(y)[i] = v;
}

extern "C" void kernel_launch(void* const* d_in, const int* in_sizes, int n_in,
                              void* d_out, int out_size, void* d_ws, size_t ws_size,
                              hipStream_t stream)
{
  const float* x     = (const float*)d_in[0];
  const float* qw    = (const float*)d_in[1];
  const float* qb    = (const float*)d_in[2];
  const float* kw    = (const float*)d_in[3];
  const float* kb    = (const float*)d_in[4];
  const float* vw    = (const float*)d_in[5];
  const float* vb    = (const float*)d_in[6];
  const float* gamma = (const float*)d_in[7];
  const float* beta  = (const float*)d_in[8];
  const float* fw    = (const float*)d_in[9];
  const float* fb    = (const float*)d_in[10];
  const float* bnw   = (const float*)d_in[11];
  const float* bnb   = (const float*)d_in[12];
  float* out = (float*)d_out;
  (void)in_sizes; (void)n_in; (void)out_size;

  char* base = (char*)d_ws;
  size_t off = 0;
  auto alloc = [&](size_t bytes)->char* {
    char* p = base + off;
    off += (bytes + 255) & ~(size_t)255;
    return p;
  };
  const long long NB = 4, Cc = 512, Nn = 4096;

  u16*   xfT  = (u16*)alloc((size_t)NB*Nn*Cc*2);     // [b][n][c]
  u16*   xfb  = (u16*)alloc((size_t)NB*Cc*Nn*2);     // [b][c][n]
  u16*   qkwb = (u16*)alloc((size_t)128*Cc*2);       // [128][512] q rows 0-63, k 64-127
  float* qkb  = (float*)alloc(128*4);
  u16*   vwb  = (u16*)alloc((size_t)Cc*Cc*2);
  u16*   fwb  = (u16*)alloc((size_t)Cc*2*Cc*2);      // [512][1024]
  u16*   qkT  = (u16*)alloc((size_t)NB*Nn*128*2);    // [b][n][128]
  u16*   vB   = (u16*)alloc((size_t)NB*Cc*Nn*2);     // [b][c][n]
  u16*   pcT  = (u16*)alloc((size_t)NB*Nn*1024*2);   // [b][n][pos 0-511 | chan 512-1023]
  float* stat = (float*)alloc((size_t)Cc*2*4);
  const size_t ATT = (size_t)Nn*Nn*2;                // one batch of att (bf16)
  int natt = (ws_size >= off + 4*ATT) ? 4 : (ws_size >= off + 2*ATT ? 2 : 1);
  u16*   att  = (u16*)alloc((size_t)natt*ATT);
  float* energy = (float*)att;                       // ALIAS: dead before att written
  u16*   catt = (u16*)((char*)att + (size_t)NB*Cc*Cc*4);

  // --- weights to bf16 (+ q/k stacked) ---
  castk<<<dim3(32),  dim3(256), 0, stream>>>(qw, qkwb, 8192);
  castk<<<dim3(32),  dim3(256), 0, stream>>>(kw, qkwb + 64*512, 8192);
  castk<<<dim3(256), dim3(256), 0, stream>>>(vw, vwb, 65536);
  castk<<<dim3(512), dim3(256), 0, stream>>>(fw, fwb, 131072);
  concat_bias<<<dim3(1), dim3(128), 0, stream>>>(qb, kb, qkb);
  // --- x -> xfb, xfT ---
  transpose_cast<<<dim3(128,16,4), dim3(32,8), 0, stream>>>(x, xfb, xfT);

  // --- projections: qkT[n,0:64]=q, [64:128]=k ; vB[c,n] ---
  gemm_bt<128,128,4,4,2,2><<<dim3(1,32,4), dim3(256), 0, stream>>>(
      xfT, Nn*Cc, 512, qkwb, 0, 512, qkT, Nn*128, 128, qkb, 512,
      nullptr, nullptr, 0, 0);
  gemm_bt<128,128,4,4,1,2><<<dim3(32,4,4), dim3(256), 0, stream>>>(
      vwb, 0, 512, xfT, Nn*Cc, 512, vB, Cc*Nn, 4096, vb, 512,
      nullptr, nullptr, 0, 0);

  // --- channel attention: energy -> softmax -> chanT (into pcT cols 512-1023) ---
  gemm_bt<64,64,2,2,0,0><<<dim3(8,8,4), dim3(256), 0, stream>>>(
      xfb, Cc*Nn, 4096, xfb, Cc*Nn, 4096, energy, Cc*Cc, 512, nullptr, 4096,
      nullptr, nullptr, 0, 0);
  softmax_rows_f32<512><<<dim3(2048), dim3(256), 0, stream>>>(energy, catt);
  gemm_bt<128,128,4,4,0,3><<<dim3(4,32,4), dim3(256), 0, stream>>>(
      xfT, Nn*Cc, 512, catt, Cc*Cc, 512, pcT + 512, Nn*1024, 1024, nullptr, 512,
      beta, xfT, Nn*Cc, 512);

  // --- position attention (batched over z) ---
  for(int pb = 0; pb < 4; pb += natt){
    int nb = (int)(4 - pb < natt ? 4 - pb : natt);
    gemm_bt<128,128,4,4,0,2><<<dim3(32,32,nb), dim3(256), 0, stream>>>(
        qkT + (long long)pb*Nn*128, Nn*128, 128,
        qkT + (long long)pb*Nn*128 + 64, Nn*128, 128,
        att, Nn*Nn, 4096, nullptr, 64, nullptr, nullptr, 0, 0);
    softmax_rows_bf16<4096><<<dim3(nb*4096), dim3(256), 0, stream>>>(att);
    // posT[n,c] = gamma * sum_j att[n,j] v[c,j] + xfT[n,c]  (into pcT cols 0-511)
    gemm_bt<128,128,4,4,0,3><<<dim3(4,32,nb), dim3(256), 0, stream>>>(
        att, Nn*Nn, 4096, vB + (long long)pb*Cc*Nn, Cc*Nn, 4096,
        pcT + (long long)pb*Nn*1024, Nn*1024, 1024, nullptr, 4096,
        gamma, xfT + (long long)pb*Nn*Cc, Nn*Cc, 512);
  }

  // --- fusion conv: y = fw . [pos|chan] + fb  (single K=1024 GEMM, f32 out) ---
  gemm_bt<128,128,4,4,1,0><<<dim3(32,4,4), dim3(256), 0, stream>>>(
      fwb, 0, 1024, pcT, Nn*1024, 1024, out, Cc*Nn, 4096, fb, 1024,
      nullptr, nullptr, 0, 0);

  // --- BN (batch stats) + ReLU ---
  bn_stats<<<dim3(512), dim3(256), 0, stream>>>(out, stat);
  bn_apply<<<dim3(8192), dim3(256), 0, stream>>>(out, stat, bnw, bnb);
}